// Round 8
// baseline (327.654 us; speedup 1.0000x reference)
//
#include <hip/hip_runtime.h>
#include <math.h>

#define EPSV 1e-5f

typedef float vfloat4 __attribute__((ext_vector_type(4)));

__device__ __forceinline__ float fast_rcp(float x) {
#if __has_builtin(__builtin_amdgcn_rcpf)
    return __builtin_amdgcn_rcpf(x);
#else
    return 1.0f / x;
#endif
}

__device__ __forceinline__ float sigmoidf_(float x) {
    return fast_rcp(1.0f + __expf(-x));
}

// ---------------------------------------------------------------------------
// K_A: per-plane row/col/plane stats. Wave-per-plane, no LDS, no barriers.
// grid = 2048 x 256 (4 waves = 4 planes per block).
// ---------------------------------------------------------------------------
__global__ __launch_bounds__(256) void k_statsA(
    const float* __restrict__ x,
    float* __restrict__ rowmean,   // [8192][64]
    float* __restrict__ colmean,   // [8192][64]
    float* __restrict__ meanA,     // [8192]
    float* __restrict__ varA)      // [8192]
{
    const int t = threadIdx.x, l = t & 63, wv = t >> 6;
    const int plane = blockIdx.x * 4 + wv;
    const float4* p4 = (const float4*)(x + (size_t)plane * 4096);
    float c0 = 0.f, c1 = 0.f, c2 = 0.f, c3 = 0.f, s = 0.f, ss = 0.f;
#pragma unroll 8
    for (int k = 0; k < 16; ++k) {
        float4 v = p4[k * 64 + l];
        float rp = v.x + v.y + v.z + v.w;
        s += rp;
        ss += v.x * v.x + v.y * v.y + v.z * v.z + v.w * v.w;
        c0 += v.x; c1 += v.y; c2 += v.z; c3 += v.w;
#pragma unroll
        for (int m = 8; m >= 1; m >>= 1) rp += __shfl_xor(rp, m, 16);
        if ((l & 15) == 0)
            rowmean[(size_t)plane * 64 + k * 4 + (l >> 4)] = rp * (1.f / 64.f);
    }
#pragma unroll
    for (int m = 32; m >= 16; m >>= 1) {
        c0 += __shfl_xor(c0, m); c1 += __shfl_xor(c1, m);
        c2 += __shfl_xor(c2, m); c3 += __shfl_xor(c3, m);
    }
    if (l < 16) {
        float4 cm = { c0 * (1.f / 64.f), c1 * (1.f / 64.f),
                      c2 * (1.f / 64.f), c3 * (1.f / 64.f) };
        ((float4*)(colmean + (size_t)plane * 64))[l] = cm;
    }
#pragma unroll
    for (int m = 32; m >= 1; m >>= 1) { s += __shfl_xor(s, m); ss += __shfl_xor(ss, m); }
    if (l == 0) {
        float mn = s * (1.f / 4096.f);
        meanA[plane] = mn;
        varA[plane] = ss * (1.f / 4096.f) - mn * mn;
    }
}

// ---------------------------------------------------------------------------
// K_BCD: per-bg fused conv1x1(B) + t-stats(C) + coefficient fold(D).
// grid = 128 (one block per bg-group) x 1024 (16 waves).
// LDS: row/col means 32 KB + gates 32 KB + stats ~1 KB.
// ---------------------------------------------------------------------------
__global__ __launch_bounds__(1024, 1) void k_bcd(
    const float* __restrict__ x,
    const float* __restrict__ W, const float* __restrict__ Wb,
    const float* __restrict__ rowmean, const float* __restrict__ colmean,
    const float* __restrict__ meanA, const float* __restrict__ varA,
    const float* __restrict__ gnw, const float* __restrict__ gnb,
    const float* __restrict__ gn1w, const float* __restrict__ gn1b,
    const float* __restrict__ cwt, const float* __restrict__ cbs,
    const float* __restrict__ swt, const float* __restrict__ sbs,
    float* __restrict__ shg, float* __restrict__ swg,
    float* __restrict__ eArr, float* __restrict__ gArr,
    float* __restrict__ dArr, float* __restrict__ aArr,
    float* __restrict__ bArr, float* __restrict__ kArr)
{
    const int bg = blockIdx.x;
    const int t = threadIdx.x, l = t & 63, wv = t >> 6;
    __shared__ float rmL[2][64][64];     // [rc][in-ch][pos]
    __shared__ float gateL[2][64][64];   // [rc][out-ch][pos], sigmoided
    __shared__ float mTl[64], vTl[64], spl[32];

    // ---- stage row/col means (coalesced) ----
#pragma unroll
    for (int j = 0; j < 4; ++j) {
        int idx = t + 1024 * j;          // 0..4095
        ((float*)rmL[0])[idx] = rowmean[(size_t)bg * 4096 + idx];
        ((float*)rmL[1])[idx] = colmean[(size_t)bg * 4096 + idx];
    }
    __syncthreads();

    // ---- phase B: 64x64 conv + sigmoid ----
    {
        const int rc = wv >> 3, cbase = (wv & 7) * 8, pos = l;
        float r[64];
#pragma unroll
        for (int i = 0; i < 64; ++i) r[i] = rmL[rc][i][pos];
#pragma unroll
        for (int j = 0; j < 8; ++j) {
            int c = cbase + j;
            float acc = Wb[c];
#pragma unroll
            for (int i = 0; i < 64; ++i) acc = fmaf(W[c * 64 + i], r[i], acc);
            float g = sigmoidf_(acc);
            gateL[rc][c][pos] = g;
            (rc ? swg : shg)[(size_t)bg * 4096 + c * 64 + pos] = g;
        }
    }
    __syncthreads();

    // ---- phase C: per-plane stats, 4 planes per wave ----
#pragma unroll
    for (int pi = 0; pi < 4; ++pi) {
        const int p = wv * 4 + pi;            // channel in group, 0..63
        const int plane = bg * 64 + p;
        const float4* p4 = (const float4*)(x + (size_t)plane * 4096);
        float4 sw4 = ((float4*)&gateL[1][p][0])[l & 15];
        float a = 0.f, bb = 0.f;
        const bool spatial = (p >= 32);
        if (spatial) {
            int i = p - 32;
            float mu = meanA[plane];
            float r2 = rsqrtf(varA[plane] + EPSV);
            a = swt[i] * gn1w[i] * r2;
            bb = swt[i] * (gn1b[i] - mu * r2 * gn1w[i]) + sbs[i];
        }
        float st = 0.f, sst = 0.f, ssp = 0.f;
#pragma unroll 8
        for (int k = 0; k < 16; ++k) {
            float4 v = p4[k * 64 + l];
            float sh = gateL[0][p][k * 4 + (l >> 4)];
            float t0 = v.x * sh * sw4.x;
            float t1 = v.y * sh * sw4.y;
            float t2 = v.z * sh * sw4.z;
            float t3 = v.w * sh * sw4.w;
            st += t0 + t1 + t2 + t3;
            sst += t0 * t0 + t1 * t1 + t2 * t2 + t3 * t3;
            if (spatial) {
                ssp += v.x * sigmoidf_(fmaf(a, v.x, bb))
                     + v.y * sigmoidf_(fmaf(a, v.y, bb))
                     + v.z * sigmoidf_(fmaf(a, v.z, bb))
                     + v.w * sigmoidf_(fmaf(a, v.w, bb));
            }
        }
#pragma unroll
        for (int m = 32; m >= 1; m >>= 1) {
            st += __shfl_xor(st, m); sst += __shfl_xor(sst, m); ssp += __shfl_xor(ssp, m);
        }
        if (l == 0) {
            float mn = st * (1.f / 4096.f);
            mTl[p] = mn;
            vTl[p] = sst * (1.f / 4096.f) - mn * mn;
            if (spatial) spl[p - 32] = ssp * (1.f / 4096.f);
        }
    }
    __syncthreads();

    // ---- phase D: coefficient fold (wave 0) ----
    if (wv == 0) {
        const int c = l;
        size_t idx = (size_t)bg * 64 + c;
        float Aj = 0.f, Bj = 0.f, scj = 0.f;
        if (c < 32) {
            float xc = meanA[idx];
            scj = sigmoidf_(fmaf(cwt[c], xc, cbs[c]));
            Aj = scj * xc;                     // mean of x_channel[c]
            Bj = spl[c];                       // mean of x_spatial[c]
        }
        float As = __shfl(Aj, c >> 1);
        float Bs = __shfl(Bj, c >> 1);
        float v2 = (c & 1) ? Bs : As;          // x2 channel mean
        // x11 = softmax(gn_b)
        float v1 = gnb[c];
        float mx = v1;
#pragma unroll
        for (int m = 32; m >= 1; m >>= 1) mx = fmaxf(mx, __shfl_xor(mx, m));
        float e1 = __expf(v1 - mx);
        float s1 = e1;
#pragma unroll
        for (int m = 32; m >= 1; m >>= 1) s1 += __shfl_xor(s1, m);
        float x11 = e1 / s1;
        // x21 = softmax(x2 channel means)
        mx = v2;
#pragma unroll
        for (int m = 32; m >= 1; m >>= 1) mx = fmaxf(mx, __shfl_xor(mx, m));
        float e2 = __expf(v2 - mx);
        float s2 = e2;
#pragma unroll
        for (int m = 32; m >= 1; m >>= 1) s2 += __shfl_xor(s2, m);
        float x21 = e2 / s2;

        float mT = mTl[c];
        float rt = rsqrtf(vTl[c] + EPSV);
        float e_c = x21 * gnw[c] * rt;
        float kp = x21 * (gnb[c] - gnw[c] * rt * mT);
#pragma unroll
        for (int m = 32; m >= 1; m >>= 1) kp += __shfl_xor(kp, m);
        float x11e = __shfl(x11, (2 * c) & 63);
        float x11o = __shfl(x11, (2 * c + 1) & 63);
        eArr[idx] = e_c;
        if (c == 0) kArr[bg] = kp;
        if (c < 32) {
            gArr[bg * 32 + c] = x11e * scj;
            dArr[bg * 32 + c] = x11o;
            size_t idx2 = (size_t)bg * 64 + 32 + c;
            float mu = meanA[idx2];
            float r2 = rsqrtf(varA[idx2] + EPSV);
            aArr[bg * 32 + c] = swt[c] * gn1w[c] * r2;
            bArr[bg * 32 + c] = swt[c] * (gn1b[c] - mu * r2 * gn1w[c]) + sbs[c];
        }
    }
}

// ---------------------------------------------------------------------------
// K_E3: weights + output; SINGLE x read; coefficients from global.
// grid = 2048 (bg*16 + band of 4 rows) x 256.
// ---------------------------------------------------------------------------
__global__ __launch_bounds__(256, 4) void k_final3(
    const float* __restrict__ x,
    const float* __restrict__ shg, const float* __restrict__ swg,
    const float* __restrict__ eArr, const float* __restrict__ gArr,
    const float* __restrict__ dArr, const float* __restrict__ aArr,
    const float* __restrict__ bArr, const float* __restrict__ kArr,
    float* __restrict__ outp)
{
    const int blk = blockIdx.x;
    const int bg = blk >> 4, band = blk & 15;
    const int h0 = band << 2;                 // 4 rows per block
    const int t = threadIdx.x, l = t & 63, wv = t >> 6;

    __shared__ float swf[64 * 64];            // 16 KB  w-gates whole bg
    __shared__ float shf[64 * 4];             //  1 KB  h-gates [c*4 + r]
    __shared__ float eL[64], gL[32], dL[32], aL[32], bL[32];
    __shared__ float4 red[4][64];             //  4 KB  partial sums
    __shared__ float4 sig4[64];               //  1 KB  sigmoid(weights)

    // ---- staging ----
#pragma unroll
    for (int j = 0; j < 4; ++j) {
        int f = t + 256 * j;
        ((float4*)swf)[f] = ((const float4*)(swg + (size_t)bg * 4096))[f];
    }
    {
        int c = t >> 2, r = t & 3;
        shf[t] = shg[(size_t)bg * 4096 + c * 64 + h0 + r];
    }
    if (t < 64)       eL[t]       = eArr[(size_t)bg * 64 + t];
    else if (t < 96)  gL[t - 64]  = gArr[bg * 32 + t - 64];
    else if (t < 128) dL[t - 96]  = dArr[bg * 32 + t - 96];
    else if (t < 160) aL[t - 128] = aArr[bg * 32 + t - 128];
    else if (t < 192) bL[t - 160] = bArr[bg * 32 + t - 160];
    const float K = kArr[bg];
    __syncthreads();

    // ---- main: cache x, partial weight sums ----
    const int r = l >> 4, qc = l & 15;
    const float* xp = x + (size_t)bg * 262144 + (size_t)(h0 + r) * 64 + qc * 4;
    const int c0 = wv * 16;
    float4 xc[16];
    float4 part = {0.f, 0.f, 0.f, 0.f};
    if (wv < 2) {
#pragma unroll
        for (int cc = 0; cc < 16; ++cc) {
            int c = c0 + cc;
            float4 v = *(const float4*)(xp + (size_t)c * 4096);
            xc[cc] = v;
            float ce = eL[c] * shf[c * 4 + r];
            float gc = gL[c];
            float4 s4 = *(const float4*)&swf[c * 64 + qc * 4];
            part.x = fmaf(fmaf(ce, s4.x, gc), v.x, part.x);
            part.y = fmaf(fmaf(ce, s4.y, gc), v.y, part.y);
            part.z = fmaf(fmaf(ce, s4.z, gc), v.z, part.z);
            part.w = fmaf(fmaf(ce, s4.w, gc), v.w, part.w);
        }
    } else {
#pragma unroll
        for (int cc = 0; cc < 16; ++cc) {
            int c = c0 + cc;
            int i = c - 32;
            float4 v = *(const float4*)(xp + (size_t)c * 4096);
            xc[cc] = v;
            float ce = eL[c] * shf[c * 4 + r];
            float ai = aL[i], bi = bL[i], di = dL[i];
            float4 s4 = *(const float4*)&swf[c * 64 + qc * 4];
            part.x = fmaf(ce * s4.x, v.x, part.x);
            part.x = fmaf(di * v.x, sigmoidf_(fmaf(ai, v.x, bi)), part.x);
            part.y = fmaf(ce * s4.y, v.y, part.y);
            part.y = fmaf(di * v.y, sigmoidf_(fmaf(ai, v.y, bi)), part.y);
            part.z = fmaf(ce * s4.z, v.z, part.z);
            part.z = fmaf(di * v.z, sigmoidf_(fmaf(ai, v.z, bi)), part.z);
            part.w = fmaf(ce * s4.w, v.w, part.w);
            part.w = fmaf(di * v.w, sigmoidf_(fmaf(ai, v.w, bi)), part.w);
        }
    }
    red[wv][l] = part;
    __syncthreads();
    if (wv == 0) {
        float4 p0 = red[0][l], p1 = red[1][l], p2 = red[2][l], p3 = red[3][l];
        float4 sgv;
        sgv.x = sigmoidf_(K + p0.x + p1.x + p2.x + p3.x);
        sgv.y = sigmoidf_(K + p0.y + p1.y + p2.y + p3.y);
        sgv.z = sigmoidf_(K + p0.z + p1.z + p2.z + p3.z);
        sgv.w = sigmoidf_(K + p0.w + p1.w + p2.w + p3.w);
        sig4[l] = sgv;
    }
    __syncthreads();
    const float4 sg = sig4[l];
    float* op = outp + (xp - x);
#pragma unroll
    for (int cc = 0; cc < 16; ++cc) {
        int c = c0 + cc;
        float4 v = xc[cc];
        vfloat4 o = { v.x * sg.x, v.y * sg.y, v.z * sg.z, v.w * sg.w };
        __builtin_nontemporal_store(o, (vfloat4*)(op + (size_t)c * 4096));
    }
}

// ---------------------------------------------------------------------------
extern "C" void kernel_launch(void* const* d_in, const int* in_sizes, int n_in,
                              void* d_out, int out_size, void* d_ws, size_t ws_size,
                              hipStream_t stream) {
    (void)in_sizes; (void)n_in; (void)out_size; (void)ws_size;
    const float* x    = (const float*)d_in[0];
    const float* W    = (const float*)d_in[1];
    const float* Wb   = (const float*)d_in[2];
    const float* gnw  = (const float*)d_in[3];
    const float* gnb  = (const float*)d_in[4];
    const float* gn1w = (const float*)d_in[5];
    const float* gn1b = (const float*)d_in[6];
    const float* cwt  = (const float*)d_in[7];
    const float* cbs  = (const float*)d_in[8];
    const float* swt  = (const float*)d_in[9];
    const float* sbs  = (const float*)d_in[10];
    float* out = (float*)d_out;
    float* ws = (float*)d_ws;

    float* rowmean = ws;                    // [8192][64]
    float* colmean = rowmean + 524288;
    float* shg     = colmean + 524288;      // sigmoided gates
    float* swg     = shg + 524288;
    float* meanA   = swg + 524288;
    float* varA    = meanA + 8192;
    float* eArr    = varA + 8192;           // [128][64]
    float* gArr    = eArr + 8192;           // [128][32]
    float* dArr    = gArr + 4096;
    float* aArr    = dArr + 4096;
    float* bArr    = aArr + 4096;
    float* kArr    = bArr + 4096;           // [128]

    k_statsA<<<2048, 256, 0, stream>>>(x, rowmean, colmean, meanA, varA);
    k_bcd<<<128, 1024, 0, stream>>>(x, W, Wb, rowmean, colmean, meanA, varA,
                                    gnw, gnb, gn1w, gn1b, cwt, cbs, swt, sbs,
                                    shg, swg, eArr, gArr, dArr, aArr, bArr, kArr);
    k_final3<<<2048, 256, 0, stream>>>(x, shg, swg, eArr, gArr, dArr, aArr, bArr,
                                       kArr, out);
}

// Round 9
// 320.918 us; speedup vs baseline: 1.0210x; 1.0210x over previous
//
#include <hip/hip_runtime.h>
#include <math.h>

#define EPSV 1e-5f

typedef float vfloat4 __attribute__((ext_vector_type(4)));

__device__ __forceinline__ float fast_rcp(float x) {
#if __has_builtin(__builtin_amdgcn_rcpf)
    return __builtin_amdgcn_rcpf(x);
#else
    return 1.0f / x;
#endif
}

__device__ __forceinline__ float sigmoidf_(float x) {
    return fast_rcp(1.0f + __expf(-x));
}

// ---------------------------------------------------------------------------
// K_A: per-plane row/col/plane stats. Wave-per-plane, no LDS, no barriers.
// grid = 2048 x 256 (4 waves = 4 planes per block).
// All 16 float4 loads issued up front (pure streaming); reductions after.
// ---------------------------------------------------------------------------
__global__ __launch_bounds__(256) void k_statsA(
    const float* __restrict__ x,
    float* __restrict__ rowmean,   // [8192][64]
    float* __restrict__ colmean,   // [8192][64]
    float* __restrict__ meanA,     // [8192]
    float* __restrict__ varA)      // [8192]
{
    const int t = threadIdx.x, l = t & 63, wv = t >> 6;
    const int plane = blockIdx.x * 4 + wv;
    const float4* p4 = (const float4*)(x + (size_t)plane * 4096);

    float4 v[16];
#pragma unroll
    for (int k = 0; k < 16; ++k) v[k] = p4[k * 64 + l];

    float c0 = 0.f, c1 = 0.f, c2 = 0.f, c3 = 0.f, s = 0.f, ss = 0.f;
    float rp[16];
#pragma unroll
    for (int k = 0; k < 16; ++k) {
        float4 vv = v[k];
        float r = vv.x + vv.y + vv.z + vv.w;
        rp[k] = r;
        s += r;
        ss += vv.x * vv.x + vv.y * vv.y + vv.z * vv.z + vv.w * vv.w;
        c0 += vv.x; c1 += vv.y; c2 += vv.z; c3 += vv.w;
    }
    // row sums: reduce across the 16 lanes of each row
#pragma unroll
    for (int k = 0; k < 16; ++k) {
        float r = rp[k];
#pragma unroll
        for (int m = 8; m >= 1; m >>= 1) r += __shfl_xor(r, m, 16);
        if ((l & 15) == 0)
            rowmean[(size_t)plane * 64 + k * 4 + (l >> 4)] = r * (1.f / 64.f);
    }
    // column sums
#pragma unroll
    for (int m = 32; m >= 16; m >>= 1) {
        c0 += __shfl_xor(c0, m); c1 += __shfl_xor(c1, m);
        c2 += __shfl_xor(c2, m); c3 += __shfl_xor(c3, m);
    }
    if (l < 16) {
        float4 cm = { c0 * (1.f / 64.f), c1 * (1.f / 64.f),
                      c2 * (1.f / 64.f), c3 * (1.f / 64.f) };
        ((float4*)(colmean + (size_t)plane * 64))[l] = cm;
    }
    // plane mean/var
#pragma unroll
    for (int m = 32; m >= 1; m >>= 1) { s += __shfl_xor(s, m); ss += __shfl_xor(ss, m); }
    if (l == 0) {
        float mn = s * (1.f / 4096.f);
        meanA[plane] = mn;
        varA[plane] = ss * (1.f / 4096.f) - mn * mn;
    }
}

// ---------------------------------------------------------------------------
// K_B: 64x64 conv1x1 over row/col means + sigmoid. grid = 256 x 256.
// ---------------------------------------------------------------------------
__global__ __launch_bounds__(256) void k_conv(
    const float* __restrict__ W, const float* __restrict__ Wb,
    const float* __restrict__ rowmean, const float* __restrict__ colmean,
    float* __restrict__ shg, float* __restrict__ swg)
{
    int blk = blockIdx.x;
    int bg = blk >> 1, rc = blk & 1;
    const float* rm = (rc ? colmean : rowmean) + (size_t)bg * 4096;
    float* outp = (rc ? swg : shg) + (size_t)bg * 4096;
    int t = threadIdx.x, lane = t & 63, wv = t >> 6;
    float r[64];
#pragma unroll
    for (int i = 0; i < 64; ++i) r[i] = rm[i * 64 + lane];
    for (int j = 0; j < 16; ++j) {
        int c = wv * 16 + j;
        float acc = Wb[c];
#pragma unroll
        for (int i = 0; i < 64; ++i)
            acc = fmaf(W[c * 64 + i], r[i], acc);
        outp[c * 64 + lane] = sigmoidf_(acc);
    }
}

// ---------------------------------------------------------------------------
// K_C: stats of t = x*sh*sw; spatial channel means. Wave-per-plane.
// grid = 2048 x 256. Loads hoisted: x and sh gates staged to registers first.
// ---------------------------------------------------------------------------
__global__ __launch_bounds__(256) void k_statsC(
    const float* __restrict__ x,
    const float* __restrict__ shg, const float* __restrict__ swg,
    const float* __restrict__ meanA, const float* __restrict__ varA,
    const float* __restrict__ swt, const float* __restrict__ sbs,
    const float* __restrict__ gn1w, const float* __restrict__ gn1b,
    float* __restrict__ meanT, float* __restrict__ varT,
    float* __restrict__ spat)   // [128][32]
{
    const int t = threadIdx.x, l = t & 63, wv = t >> 6;
    const int plane = blockIdx.x * 4 + wv;
    const int cch = plane & 63, bgc = plane >> 6;
    const float4* p4 = (const float4*)(x + (size_t)plane * 4096);

    float4 v[16];
#pragma unroll
    for (int k = 0; k < 16; ++k) v[k] = p4[k * 64 + l];
    float sh16[16];
#pragma unroll
    for (int k = 0; k < 16; ++k)
        sh16[k] = shg[(size_t)plane * 64 + k * 4 + (l >> 4)];
    float4 sw4 = ((const float4*)(swg + (size_t)plane * 64))[l & 15];

    float a = 0.f, bb = 0.f;
    const bool spatial = (cch >= 32);
    if (spatial) {
        int i = cch - 32;
        float mu = meanA[plane];
        float r2 = rsqrtf(varA[plane] + EPSV);
        a = swt[i] * gn1w[i] * r2;
        bb = swt[i] * (gn1b[i] - mu * r2 * gn1w[i]) + sbs[i];
    }
    float st = 0.f, sst = 0.f, ssp = 0.f;
#pragma unroll
    for (int k = 0; k < 16; ++k) {
        float4 vv = v[k];
        float sh = sh16[k];
        float t0 = vv.x * sh * sw4.x;
        float t1 = vv.y * sh * sw4.y;
        float t2 = vv.z * sh * sw4.z;
        float t3 = vv.w * sh * sw4.w;
        st += t0 + t1 + t2 + t3;
        sst += t0 * t0 + t1 * t1 + t2 * t2 + t3 * t3;
        if (spatial) {
            ssp += vv.x * sigmoidf_(fmaf(a, vv.x, bb))
                 + vv.y * sigmoidf_(fmaf(a, vv.y, bb))
                 + vv.z * sigmoidf_(fmaf(a, vv.z, bb))
                 + vv.w * sigmoidf_(fmaf(a, vv.w, bb));
        }
    }
#pragma unroll
    for (int m = 32; m >= 1; m >>= 1) {
        st += __shfl_xor(st, m); sst += __shfl_xor(sst, m); ssp += __shfl_xor(ssp, m);
    }
    if (l == 0) {
        float mn = st * (1.f / 4096.f);
        meanT[plane] = mn;
        varT[plane] = sst * (1.f / 4096.f) - mn * mn;
        if (spatial) spat[bgc * 32 + (cch - 32)] = ssp * (1.f / 4096.f);
    }
}

// ---------------------------------------------------------------------------
// K_E2: fused coefficient-fold (wave 0) + weights + output; SINGLE x read.
// grid = 2048 (bg*16 + band of 4 rows) x 256.  (verbatim round-7 version)
// ---------------------------------------------------------------------------
__global__ __launch_bounds__(256, 4) void k_final2(
    const float* __restrict__ x,
    const float* __restrict__ shg, const float* __restrict__ swg,
    const float* __restrict__ meanA, const float* __restrict__ varA,
    const float* __restrict__ meanT, const float* __restrict__ varT,
    const float* __restrict__ spat,
    const float* __restrict__ gnw, const float* __restrict__ gnb,
    const float* __restrict__ gn1w, const float* __restrict__ gn1b,
    const float* __restrict__ cwt, const float* __restrict__ cbs,
    const float* __restrict__ swt, const float* __restrict__ sbs,
    float* __restrict__ outp)
{
    const int blk = blockIdx.x;
    const int bg = blk >> 4, band = blk & 15;
    const int h0 = band << 2;                 // 4 rows per block
    const int t = threadIdx.x, l = t & 63, wv = t >> 6;

    __shared__ float swf[64 * 64];            // 16 KB  w-gates whole bg
    __shared__ float shf[64 * 4];             //  1 KB  h-gates [c*4 + r]
    __shared__ float eL[64], gL[32], dL[32], aL[32], bL[32];
    __shared__ float kS;
    __shared__ float4 red[4][64];             //  4 KB  partial sums
    __shared__ float4 sig4[64];               //  1 KB  sigmoid(weights)

    // ---- staging (all waves) ----
#pragma unroll
    for (int j = 0; j < 4; ++j) {
        int f = t + 256 * j;
        ((float4*)swf)[f] = ((const float4*)(swg + (size_t)bg * 4096))[f];
    }
    {
        int c = t >> 2, r = t & 3;
        shf[t] = shg[(size_t)bg * 4096 + c * 64 + h0 + r];
    }

    // ---- D-compute (wave 0 only) ----
    if (wv == 0) {
        const int c = l;
        size_t idx = (size_t)bg * 64 + c;
        float Aj = 0.f, Bj = 0.f, scj = 0.f;
        if (c < 32) {
            float xc = meanA[idx];
            scj = sigmoidf_(fmaf(cwt[c], xc, cbs[c]));
            Aj = scj * xc;                     // mean of x_channel[c]
            Bj = spat[bg * 32 + c];            // mean of x_spatial[c]
        }
        float As = __shfl(Aj, c >> 1);
        float Bs = __shfl(Bj, c >> 1);
        float v2 = (c & 1) ? Bs : As;          // x2 channel mean
        // x11 = softmax(gn_b)
        float v1 = gnb[c];
        float mx = v1;
#pragma unroll
        for (int m = 32; m >= 1; m >>= 1) mx = fmaxf(mx, __shfl_xor(mx, m));
        float e1 = __expf(v1 - mx);
        float s1 = e1;
#pragma unroll
        for (int m = 32; m >= 1; m >>= 1) s1 += __shfl_xor(s1, m);
        float x11 = e1 / s1;
        // x21 = softmax(x2 channel means)
        mx = v2;
#pragma unroll
        for (int m = 32; m >= 1; m >>= 1) mx = fmaxf(mx, __shfl_xor(mx, m));
        float e2 = __expf(v2 - mx);
        float s2 = e2;
#pragma unroll
        for (int m = 32; m >= 1; m >>= 1) s2 += __shfl_xor(s2, m);
        float x21 = e2 / s2;

        float mT = meanT[idx];
        float rt = rsqrtf(varT[idx] + EPSV);
        float e_c = x21 * gnw[c] * rt;
        float kp = x21 * (gnb[c] - gnw[c] * rt * mT);
#pragma unroll
        for (int m = 32; m >= 1; m >>= 1) kp += __shfl_xor(kp, m);
        float x11e = __shfl(x11, (2 * c) & 63);
        float x11o = __shfl(x11, (2 * c + 1) & 63);
        eL[c] = e_c;
        if (c == 0) kS = kp;
        if (c < 32) {
            gL[c] = x11e * scj;
            dL[c] = x11o;
            size_t idx2 = (size_t)bg * 64 + 32 + c;
            float mu = meanA[idx2];
            float r2 = rsqrtf(varA[idx2] + EPSV);
            aL[c] = swt[c] * gn1w[c] * r2;
            bL[c] = swt[c] * (gn1b[c] - mu * r2 * gn1w[c]) + sbs[c];
        }
    }
    __syncthreads();

    // ---- main: cache x, partial weight sums ----
    const int r = l >> 4, qc = l & 15;
    const float* xp = x + (size_t)bg * 262144 + (size_t)(h0 + r) * 64 + qc * 4;
    const int c0 = wv * 16;
    float4 xc[16];
    float4 part = {0.f, 0.f, 0.f, 0.f};
    if (wv < 2) {
#pragma unroll
        for (int cc = 0; cc < 16; ++cc) {
            int c = c0 + cc;
            float4 v = *(const float4*)(xp + (size_t)c * 4096);
            xc[cc] = v;
            float ce = eL[c] * shf[c * 4 + r];
            float gc = gL[c];
            float4 s4 = *(const float4*)&swf[c * 64 + qc * 4];
            part.x = fmaf(fmaf(ce, s4.x, gc), v.x, part.x);
            part.y = fmaf(fmaf(ce, s4.y, gc), v.y, part.y);
            part.z = fmaf(fmaf(ce, s4.z, gc), v.z, part.z);
            part.w = fmaf(fmaf(ce, s4.w, gc), v.w, part.w);
        }
    } else {
#pragma unroll
        for (int cc = 0; cc < 16; ++cc) {
            int c = c0 + cc;
            int i = c - 32;
            float4 v = *(const float4*)(xp + (size_t)c * 4096);
            xc[cc] = v;
            float ce = eL[c] * shf[c * 4 + r];
            float ai = aL[i], bi = bL[i], di = dL[i];
            float4 s4 = *(const float4*)&swf[c * 64 + qc * 4];
            part.x = fmaf(ce * s4.x, v.x, part.x);
            part.x = fmaf(di * v.x, sigmoidf_(fmaf(ai, v.x, bi)), part.x);
            part.y = fmaf(ce * s4.y, v.y, part.y);
            part.y = fmaf(di * v.y, sigmoidf_(fmaf(ai, v.y, bi)), part.y);
            part.z = fmaf(ce * s4.z, v.z, part.z);
            part.z = fmaf(di * v.z, sigmoidf_(fmaf(ai, v.z, bi)), part.z);
            part.w = fmaf(ce * s4.w, v.w, part.w);
            part.w = fmaf(di * v.w, sigmoidf_(fmaf(ai, v.w, bi)), part.w);
        }
    }
    red[wv][l] = part;
    __syncthreads();
    if (wv == 0) {
        float4 p0 = red[0][l], p1 = red[1][l], p2 = red[2][l], p3 = red[3][l];
        float K = kS;
        float4 sgv;
        sgv.x = sigmoidf_(K + p0.x + p1.x + p2.x + p3.x);
        sgv.y = sigmoidf_(K + p0.y + p1.y + p2.y + p3.y);
        sgv.z = sigmoidf_(K + p0.z + p1.z + p2.z + p3.z);
        sgv.w = sigmoidf_(K + p0.w + p1.w + p2.w + p3.w);
        sig4[l] = sgv;
    }
    __syncthreads();
    const float4 sg = sig4[l];
    float* op = outp + (xp - x);
#pragma unroll
    for (int cc = 0; cc < 16; ++cc) {
        int c = c0 + cc;
        float4 v = xc[cc];
        vfloat4 o = { v.x * sg.x, v.y * sg.y, v.z * sg.z, v.w * sg.w };
        __builtin_nontemporal_store(o, (vfloat4*)(op + (size_t)c * 4096));
    }
}

// ---------------------------------------------------------------------------
extern "C" void kernel_launch(void* const* d_in, const int* in_sizes, int n_in,
                              void* d_out, int out_size, void* d_ws, size_t ws_size,
                              hipStream_t stream) {
    (void)in_sizes; (void)n_in; (void)out_size; (void)ws_size;
    const float* x    = (const float*)d_in[0];
    const float* W    = (const float*)d_in[1];
    const float* Wb   = (const float*)d_in[2];
    const float* gnw  = (const float*)d_in[3];
    const float* gnb  = (const float*)d_in[4];
    const float* gn1w = (const float*)d_in[5];
    const float* gn1b = (const float*)d_in[6];
    const float* cwt  = (const float*)d_in[7];
    const float* cbs  = (const float*)d_in[8];
    const float* swt  = (const float*)d_in[9];
    const float* sbs  = (const float*)d_in[10];
    float* out = (float*)d_out;
    float* ws = (float*)d_ws;

    float* rowmean = ws;                    // [8192][64]
    float* colmean = rowmean + 524288;
    float* shg     = colmean + 524288;      // sigmoided gates
    float* swg     = shg + 524288;
    float* meanA   = swg + 524288;
    float* varA    = meanA + 8192;
    float* meanT   = varA + 8192;
    float* varT    = meanT + 8192;
    float* spat    = varT + 8192;

    k_statsA<<<2048, 256, 0, stream>>>(x, rowmean, colmean, meanA, varA);
    k_conv<<<256, 256, 0, stream>>>(W, Wb, rowmean, colmean, shg, swg);
    k_statsC<<<2048, 256, 0, stream>>>(x, shg, swg, meanA, varA, swt, sbs, gn1w, gn1b,
                                       meanT, varT, spat);
    k_final2<<<2048, 256, 0, stream>>>(x, shg, swg, meanA, varA, meanT, varT, spat,
                                       gnw, gnb, gn1w, gn1b, cwt, cbs, swt, sbs, out);
}